// Round 8
// baseline (780.346 us; speedup 1.0000x reference)
//
#include <hip/hip_runtime.h>
#include <hip/hip_bf16.h>

#define NN  100000
#define NE  1600000
#define NH4 400000      // N*H
#define NHC 12800000    // N*HC
#define NBLK 391        // ceil(NN/256)
#define SC_CHUNK 2048
#define SC_NCHUNK ((NE + SC_CHUNK - 1) / SC_CHUNK)  // 782

__device__ __forceinline__ ushort f2bf(float f) {  // RNE f32 -> bf16 bits
  uint u = __float_as_uint(f);
  u += 0x7fff + ((u >> 16) & 1);
  return (ushort)(u >> 16);
}

// ---- GEMM: out[N,128] = A[N,128] @ W[128,128] (+ bias1 + bias2) ----
// Tile: 64 rows/block, thread = 16 rows x 2 cols; As reads are wave-uniform
// broadcasts; VALU-bound.
template <bool BF16OUT>
__global__ __launch_bounds__(256) void gemm128_k(const float* __restrict__ A,
                                                 const float* __restrict__ W,
                                                 void* __restrict__ outv,
                                                 const float* __restrict__ bias1,
                                                 const float* __restrict__ bias2) {
  __shared__ float As[64 * 128];   // 32 KB
  __shared__ float Wsh[64 * 128];  // 32 KB
  const int tid = threadIdx.x;
  const int row0 = blockIdx.x * 64;
  {
    const float4* __restrict__ Ag = (const float4*)(A + (size_t)row0 * 128);
    float4* Al = (float4*)As;
#pragma unroll
    for (int i = 0; i < 8; i++) {
      const int idx = tid + 256 * i;          // float4 index; row = idx>>5
      Al[idx] = (row0 + (idx >> 5) < NN) ? Ag[idx] : make_float4(0.f, 0.f, 0.f, 0.f);
    }
  }

  const int c2 = tid & 63;   // cols c2 and c2+64
  const int rh = tid >> 6;   // row group rh*16..+15 (uniform per wave)
  float acc[16][2];
#pragma unroll
  for (int j = 0; j < 16; j++) acc[j][0] = acc[j][1] = 0.f;

  for (int kt = 0; kt < 2; kt++) {
    {
      const float4* __restrict__ Wg = (const float4*)(W + kt * 64 * 128);
      float4* Wl = (float4*)Wsh;
      __syncthreads();
#pragma unroll
      for (int i = 0; i < 8; i++) Wl[tid + 256 * i] = Wg[tid + 256 * i];
      __syncthreads();
    }
#pragma unroll 2
    for (int kk = 0; kk < 64; kk += 4) {
      const int k = kt * 64 + kk;
      float wa[4], wb[4];
#pragma unroll
      for (int q = 0; q < 4; q++) {
        wa[q] = Wsh[(kk + q) * 128 + c2];
        wb[q] = Wsh[(kk + q) * 128 + c2 + 64];
      }
#pragma unroll
      for (int j = 0; j < 16; j++) {
        const float4 a = *(const float4*)&As[(rh * 16 + j) * 128 + k];  // broadcast
        acc[j][0] = fmaf(a.x, wa[0], acc[j][0]);
        acc[j][1] = fmaf(a.x, wb[0], acc[j][1]);
        acc[j][0] = fmaf(a.y, wa[1], acc[j][0]);
        acc[j][1] = fmaf(a.y, wb[1], acc[j][1]);
        acc[j][0] = fmaf(a.z, wa[2], acc[j][0]);
        acc[j][1] = fmaf(a.z, wb[2], acc[j][1]);
        acc[j][0] = fmaf(a.w, wa[3], acc[j][0]);
        acc[j][1] = fmaf(a.w, wb[3], acc[j][1]);
      }
    }
  }
  float ba = 0.f, bb = 0.f;
  if (bias1) { ba += bias1[c2]; bb += bias1[c2 + 64]; }
  if (bias2) { ba += bias2[c2]; bb += bias2[c2 + 64]; }
#pragma unroll
  for (int j = 0; j < 16; j++) {
    const int r = row0 + rh * 16 + j;
    if (r >= NN) break;
    if constexpr (BF16OUT) {
      ushort* out = (ushort*)outv;
      out[(size_t)r * 128 + c2]      = f2bf(acc[j][0] + ba);
      out[(size_t)r * 128 + c2 + 64] = f2bf(acc[j][1] + bb);
    } else {
      float* out = (float*)outv;
      out[(size_t)r * 128 + c2]      = acc[j][0] + ba;
      out[(size_t)r * 128 + c2 + 64] = acc[j][1] + bb;
    }
  }
}

// ---- attention coefficients from bf16 xh ----
__global__ __launch_bounds__(256) void attn_coef_k(const uint* __restrict__ xbf,
                                                   const float* __restrict__ as_,
                                                   const float* __restrict__ ad_,
                                                   float* __restrict__ es,
                                                   float* __restrict__ ed) {
  const int idx = blockIdx.x * 256 + threadIdx.x;
  if (idx >= NH4) return;
  const int h = idx & 3;
  const int ab = h * 32;
  const uint* row = xbf + (size_t)(idx >> 2) * 64 + h * 16;
  float s = 0.f, d = 0.f;
#pragma unroll
  for (int i = 0; i < 16; i += 4) {
    const uint4 v = *(const uint4*)(row + i);
#define UNP(u, k)                                                        \
    {                                                                    \
      const float lo = __uint_as_float((u) << 16);                       \
      const float hi = __uint_as_float((u) & 0xffff0000u);               \
      s = fmaf(lo, as_[ab + (k)], fmaf(hi, as_[ab + (k) + 1], s));       \
      d = fmaf(lo, ad_[ab + (k)], fmaf(hi, ad_[ab + (k) + 1], d));       \
    }
    UNP(v.x, 2 * i) UNP(v.y, 2 * i + 2) UNP(v.z, 2 * i + 4) UNP(v.w, 2 * i + 6)
#undef UNP
  }
  es[idx] = s;
  ed[idx] = d;
}

// ---- CSR build: XCD-partitioned histogram (dst range per blockIdx&7 keeps
// each counts line in one XCD's L2) ----
__global__ __launch_bounds__(256) void hist_k(const int* __restrict__ dst, int* __restrict__ counts) {
  const int g = blockIdx.x & 7;
  const int chunk = blockIdx.x >> 3;
  const int lo = g * (NN / 8);
  const int hi = lo + (NN / 8);
  const int e0 = chunk * SC_CHUNK;
  const int e1 = (e0 + SC_CHUNK < NE) ? e0 + SC_CHUNK : NE;
  for (int i = e0 + threadIdx.x; i < e1; i += 256) {
    const int d = dst[i];
    if (d >= lo && d < hi) atomicAdd(&counts[d], 1);
  }
}

// ---- two-level scan ----
__global__ __launch_bounds__(256) void scan_blk_k(const int* __restrict__ counts,
                                                  int* __restrict__ row_start,
                                                  int* __restrict__ blocksum) {
  __shared__ int sm[256];
  const int t = threadIdx.x;
  const int i = blockIdx.x * 256 + t;
  const int c = (i < NN) ? counts[i] : 0;
  sm[t] = c;
  __syncthreads();
#pragma unroll
  for (int off = 1; off < 256; off <<= 1) {
    const int v = (t >= off) ? sm[t - off] : 0;
    __syncthreads();
    sm[t] += v;
    __syncthreads();
  }
  if (i < NN) row_start[i] = sm[t] - c;
  if (t == 255) blocksum[blockIdx.x] = sm[255];
}

__global__ __launch_bounds__(512) void scan_top_k(const int* __restrict__ blocksum,
                                                  int* __restrict__ blockoff) {
  __shared__ int sm[512];
  const int t = threadIdx.x;
  const int c = (t < NBLK) ? blocksum[t] : 0;
  sm[t] = c;
  __syncthreads();
#pragma unroll
  for (int off = 1; off < 512; off <<= 1) {
    const int v = (t >= off) ? sm[t - off] : 0;
    __syncthreads();
    sm[t] += v;
    __syncthreads();
  }
  if (t < NBLK) blockoff[t] = sm[t] - c;
}

__global__ __launch_bounds__(256) void scan_fix_k(int* __restrict__ row_start,
                                                  const int* __restrict__ blockoff,
                                                  int* __restrict__ cursor) {
  const int i = blockIdx.x * 256 + threadIdx.x;
  if (i < NN) {
    const int v = row_start[i] + blockoff[blockIdx.x];
    row_start[i] = v;
    cursor[i] = v;
  }
  if (i == 0) row_start[NN] = NE;
}

// ---- XCD-partitioned scatter ----
__global__ __launch_bounds__(256) void scatter_k(const int* __restrict__ src,
                                                 const int* __restrict__ dst,
                                                 int* __restrict__ cursor,
                                                 int* __restrict__ csr_src) {
  const int g = blockIdx.x & 7;
  const int chunk = blockIdx.x >> 3;
  const int lo = g * (NN / 8);
  const int hi = lo + (NN / 8);
  const int e0 = chunk * SC_CHUNK;
  const int e1 = (e0 + SC_CHUNK < NE) ? e0 + SC_CHUNK : NE;
  for (int i = e0 + threadIdx.x; i < e1; i += 256) {
    const int d = dst[i];
    if (d >= lo && d < hi) {
      const int pos = atomicAdd(&cursor[d], 1);
      csr_src[pos] = src[i];
    }
  }
}

// ---- fused GAT aggregation: one wave per dst node, bf16 gathers, 8-way ILP ----
#define EDGE_BODY(sv)                                                      \
  {                                                                        \
    const int s_ = (sv);                                                   \
    float v_ = es[s_ * 4 + h] + edh;                                       \
    v_ = v_ > 0.f ? v_ : 0.2f * v_;                                        \
    const float w_ = __expf(v_);                                           \
    const uint m_ = xbf[(size_t)s_ * 64 + l];                              \
    const float mx = __uint_as_float(m_ << 16);                            \
    const float my = __uint_as_float(m_ & 0xffff0000u);                    \
    den += w_;                                                             \
    ax = fmaf(w_, mx, ax);                                                 \
    ay = fmaf(w_, my, ay);                                                 \
  }

__global__ __launch_bounds__(256) void gat_agg_k(const int* __restrict__ row_start,
                                                 const int* __restrict__ csr_src,
                                                 const float* __restrict__ es,
                                                 const float* __restrict__ ed,
                                                 const uint* __restrict__ xbf,
                                                 const float* __restrict__ base,
                                                 const float* __restrict__ bias,
                                                 float* __restrict__ out) {
  const int wid = (blockIdx.x * 256 + threadIdx.x) >> 6;  // node id
  if (wid >= NN) return;
  const int l = threadIdx.x & 63;   // lane: channels 2l (lo), 2l+1 (hi)
  const int h = l >> 4;             // head of both channels
  const float edh = ed[wid * 4 + h];
  const int beg = row_start[wid], end = row_start[wid + 1];
  float ax = 0.f, ay = 0.f, den = 0.f;
  int i = beg;
  for (; i + 8 <= end; i += 8) {
    const int s0 = csr_src[i],     s1 = csr_src[i + 1];
    const int s2 = csr_src[i + 2], s3 = csr_src[i + 3];
    const int s4 = csr_src[i + 4], s5 = csr_src[i + 5];
    const int s6 = csr_src[i + 6], s7 = csr_src[i + 7];
    EDGE_BODY(s0) EDGE_BODY(s1) EDGE_BODY(s2) EDGE_BODY(s3)
    EDGE_BODY(s4) EDGE_BODY(s5) EDGE_BODY(s6) EDGE_BODY(s7)
  }
  for (; i + 4 <= end; i += 4) {
    const int s0 = csr_src[i],     s1 = csr_src[i + 1];
    const int s2 = csr_src[i + 2], s3 = csr_src[i + 3];
    EDGE_BODY(s0) EDGE_BODY(s1) EDGE_BODY(s2) EDGE_BODY(s3)
  }
  for (; i < end; i++) EDGE_BODY(csr_src[i]);

  const float inv = den > 0.f ? 1.f / den : 0.f;
  float rx = ax * inv, ry = ay * inv;
  const int o = wid * 128 + l * 2;
  if (base) { rx += base[o]; ry += base[o + 1]; }
  if (bias) { rx += bias[l * 2]; ry += bias[l * 2 + 1]; }
  *(float2*)(out + o) = make_float2(rx, ry);
}

// ---- final projection: wave w of block computes channels 8w..8w+7 for 64
// nodes (lane = node). 4x waves vs one-thread-per-node -> occupancy fix.
// opW accessed wave-uniformly (readfirstlane) -> scalar loads. ----
__global__ __launch_bounds__(256) void out_proj_k(const float* __restrict__ h0,
                                                  const float* __restrict__ h1,
                                                  const float* __restrict__ h2,
                                                  const float* __restrict__ opW,
                                                  const float* __restrict__ opb,
                                                  float* __restrict__ out) {
  const int cb = __builtin_amdgcn_readfirstlane((threadIdx.x >> 6) * 8);  // channel base
  const int l = threadIdx.x & 63;
  const int n = blockIdx.x * 64 + l;
  if (n >= NN) return;

  float acc[8];
#pragma unroll
  for (int j = 0; j < 8; j++) acc[j] = opb[cb + j];

  const float4* __restrict__ r0 = (const float4*)(h0 + (size_t)n * 128);
  const float4* __restrict__ r1 = (const float4*)(h1 + (size_t)n * 128);
  const float4* __restrict__ r2 = (const float4*)(h2 + (size_t)n * 128);

#define SEG(rp, kofs)                                                         \
  for (int k4 = 0; k4 < 32; k4++) {                                           \
    const float4 a = rp[k4];                                                  \
    const float* __restrict__ wr = opW + (size_t)((kofs) + k4 * 4) * 32 + cb; \
    _Pragma("unroll") for (int j = 0; j < 8; j++)                             \
        acc[j] = fmaf(a.x, wr[j], acc[j]);                                    \
    _Pragma("unroll") for (int j = 0; j < 8; j++)                             \
        acc[j] = fmaf(a.y, wr[32 + j], acc[j]);                               \
    _Pragma("unroll") for (int j = 0; j < 8; j++)                             \
        acc[j] = fmaf(a.z, wr[64 + j], acc[j]);                               \
    _Pragma("unroll") for (int j = 0; j < 8; j++)                             \
        acc[j] = fmaf(a.w, wr[96 + j], acc[j]);                               \
  }

  SEG(r0, 0)
  SEG(r1, 128)
  SEG(r2, 256)
#undef SEG

  float* __restrict__ o = out + (size_t)n * 32 + cb;
  *(float4*)(o + 0) = make_float4(acc[0], acc[1], acc[2], acc[3]);
  *(float4*)(o + 4) = make_float4(acc[4], acc[5], acc[6], acc[7]);
}

extern "C" void kernel_launch(void* const* d_in, const int* in_sizes, int n_in,
                              void* d_out, int out_size, void* d_ws, size_t ws_size,
                              hipStream_t stream) {
  (void)in_sizes; (void)n_in; (void)out_size; (void)ws_size;
  const float* x  = (const float*)d_in[0];
  const int*   ei = (const int*)d_in[1];
  const int*  src = ei;
  const int*  dst = ei + NE;
  const float *W0 = (const float*)d_in[2],  *as0 = (const float*)d_in[3],
              *ad0 = (const float*)d_in[4], *b0 = (const float*)d_in[5];
  const float *W1 = (const float*)d_in[6],  *as1 = (const float*)d_in[7],
              *ad1 = (const float*)d_in[8], *b1 = (const float*)d_in[9];
  const float *W2 = (const float*)d_in[10], *as2 = (const float*)d_in[11],
              *ad2 = (const float*)d_in[12], *b2 = (const float*)d_in[13];
  const float *llW = (const float*)d_in[14], *llb = (const float*)d_in[15];
  const float *opW = (const float*)d_in[16], *opb = (const float*)d_in[17];

  float* ws    = (float*)d_ws;
  float* h0f   = ws;             // NHC
  float* h1f   = h0f + NHC;      // NHC
  float* h2f   = h1f + NHC;      // NHC
  uint*  xbf   = (uint*)(h2f + NHC);      // NHC/2 uints (bf16 xh)
  float* es    = (float*)(xbf + NHC / 2); // NH4
  float* ed    = es + NH4;       // NH4
  int* row_start = (int*)(ed + NH4);      // NN+1
  int* cursor    = row_start + NN + 1;    // NN
  int* counts    = cursor + NN;           // NN
  int* csr_src   = counts + NN;           // NE
  int* blocksum  = csr_src + NE;          // NBLK
  int* blockoff  = blocksum + NBLK;       // NBLK

  const dim3 blk(256);
  // ---------- CSR build (edges shared by all 3 layers) ----------
  hipMemsetAsync(counts, 0, (size_t)NN * 4, stream);
  hist_k<<<SC_NCHUNK * 8, blk, 0, stream>>>(dst, counts);
  scan_blk_k<<<NBLK, blk, 0, stream>>>(counts, row_start, blocksum);
  scan_top_k<<<1, 512, 0, stream>>>(blocksum, blockoff);
  scan_fix_k<<<NBLK, blk, 0, stream>>>(row_start, blockoff, cursor);
  scatter_k<<<SC_NCHUNK * 8, blk, 0, stream>>>(src, dst, cursor, csr_src);
  // ---------- layer 0 ----------
  gemm128_k<true><<<1563, blk, 0, stream>>>(x, W0, xbf, nullptr, nullptr);
  attn_coef_k<<<1563, blk, 0, stream>>>(xbf, as0, ad0, es, ed);
  gat_agg_k<<<25000, blk, 0, stream>>>(row_start, csr_src, es, ed, xbf, nullptr, b0, h0f);
  // ---------- layer 1 ----------
  gemm128_k<true><<<1563, blk, 0, stream>>>(h0f, W1, xbf, nullptr, nullptr);
  attn_coef_k<<<1563, blk, 0, stream>>>(xbf, as1, ad1, es, ed);
  gat_agg_k<<<25000, blk, 0, stream>>>(row_start, csr_src, es, ed, xbf, h0f, b1, h1f);
  // ---------- layer 2 ----------
  gemm128_k<false><<<1563, blk, 0, stream>>>(h1f, llW, h2f, llb, b2);  // h2 base = h1@llW + llb + b2
  gemm128_k<true><<<1563, blk, 0, stream>>>(h1f, W2, xbf, nullptr, nullptr);
  attn_coef_k<<<1563, blk, 0, stream>>>(xbf, as2, ad2, es, ed);
  gat_agg_k<<<25000, blk, 0, stream>>>(row_start, csr_src, es, ed, xbf, h2f, nullptr, h2f);
  // ---------- output head ----------
  out_proj_k<<<1563, blk, 0, stream>>>(h0f, h1f, h2f, opW, opb, (float*)d_out);
}

// Round 9
// 661.714 us; speedup vs baseline: 1.1793x; 1.1793x over previous
//
#include <hip/hip_runtime.h>
#include <hip/hip_bf16.h>

#define NN  100000
#define NE  1600000
#define NH4 400000      // N*H
#define NHC 12800000    // N*HC
#define NBLK 391        // ceil(NN/256)
#define SC_CHUNK 2048
#define SC_NCHUNK ((NE + SC_CHUNK - 1) / SC_CHUNK)  // 782

typedef __attribute__((ext_vector_type(8))) short bf16x8;
typedef __attribute__((ext_vector_type(4))) float f32x4;

__device__ __forceinline__ ushort f2bf(float f) {  // RNE f32 -> bf16 bits
  uint u = __float_as_uint(f);
  u += 0x7fff + ((u >> 16) & 1);
  return (ushort)(u >> 16);
}
__device__ __forceinline__ uint pack2(float a, float b) {
  return (uint)f2bf(a) | ((uint)f2bf(b) << 16);
}

// ---- MFMA GEMM: out[N,128] = A[N,128] @ W[128,128] (+ bias1 + bias2) ----
// 64 rows/block, 4 waves; A,W staged bf16 in LDS with XOR swizzle
// (uint_idx ^= (row&7)<<2, same on write & read). Per wave: 8 n-tiles x
// 4 k-chunks of v_mfma_f32_16x16x32_bf16.
// Frag layouts (guide §3, m89-verified): A row=l&15,k=(l>>4)*8+i;
// B col=l&15, same k; D col=l&15,row=(l>>4)*4+reg.
template <bool BF16OUT>
__global__ __launch_bounds__(256) void gemm128_k(const float* __restrict__ A,
                                                 const float* __restrict__ W,
                                                 void* __restrict__ outv,
                                                 const float* __restrict__ bias1,
                                                 const float* __restrict__ bias2) {
  __shared__ uint As[64 * 64];    // 16 KB  (row r: 64 uints = 128 bf16)
  __shared__ uint Wt[128 * 64];   // 32 KB  (row n: 64 uints = 128 bf16, k-major)
  const int tid = threadIdx.x;
  const int row0 = blockIdx.x * 64;

  // ---- stage A: f32 -> bf16, swizzled ----
  {
    const float4* __restrict__ Ag = (const float4*)(A + (size_t)row0 * 128);
#pragma unroll
    for (int i = 0; i < 8; i++) {
      const int idx = tid + 256 * i;        // float4 idx over 64x32
      const int r = idx >> 5, k4 = idx & 31;
      float4 a = make_float4(0.f, 0.f, 0.f, 0.f);
      if (row0 + r < NN) a = Ag[idx];
      uint2 p;
      p.x = pack2(a.x, a.y);
      p.y = pack2(a.z, a.w);
      const uint off = (uint)(r * 64 + k4 * 2) ^ (uint)((r & 7) << 2);
      *(uint2*)&As[off] = p;
    }
  }
  // ---- stage W transposed: Wt[n][k] bf16, swizzled ----
  {
#pragma unroll
    for (int i = 0; i < 8; i++) {
      const int cid = tid + 256 * i;        // (n, k8) chunk
      const int n = cid & 127;
      const int k8 = cid >> 7;              // 0..15
      float v[8];
#pragma unroll
      for (int j = 0; j < 8; j++) v[j] = W[(size_t)(k8 * 8 + j) * 128 + n];
      uint4 p;
      p.x = pack2(v[0], v[1]);
      p.y = pack2(v[2], v[3]);
      p.z = pack2(v[4], v[5]);
      p.w = pack2(v[6], v[7]);
      const uint off = (uint)(n * 64 + k8 * 4) ^ (uint)((n & 7) << 2);
      *(uint4*)&Wt[off] = p;
    }
  }
  __syncthreads();

  const int w = tid >> 6, l = tid & 63;
  const int lrow = l & 15;
  const int lku = (l >> 4) * 4;   // uint offset of this lane's k-base (8 bf16 = 4 uints)

  bf16x8 afrag[4];
#pragma unroll
  for (int kc = 0; kc < 4; kc++) {
    const int r = w * 16 + lrow;
    const uint off = (uint)(r * 64 + lku + kc * 16) ^ (uint)((r & 7) << 2);
    afrag[kc] = *(const bf16x8*)&As[off];
  }

#pragma unroll
  for (int nt = 0; nt < 8; nt++) {
    const int n = nt * 16 + lrow;
    f32x4 acc = {0.f, 0.f, 0.f, 0.f};
#pragma unroll
    for (int kc = 0; kc < 4; kc++) {
      const uint off = (uint)(n * 64 + lku + kc * 16) ^ (uint)((n & 7) << 2);
      const bf16x8 bfrag = *(const bf16x8*)&Wt[off];
      acc = __builtin_amdgcn_mfma_f32_16x16x32_bf16(afrag[kc], bfrag, acc, 0, 0, 0);
    }
    const int col = n;  // D col = l&15 within tile
    float badd = 0.f;
    if (bias1) badd += bias1[col];
    if (bias2) badd += bias2[col];
#pragma unroll
    for (int reg = 0; reg < 4; reg++) {
      const int r = row0 + w * 16 + (l >> 4) * 4 + reg;
      if (r < NN) {
        if constexpr (BF16OUT)
          ((ushort*)outv)[(size_t)r * 128 + col] = f2bf(acc[reg] + badd);
        else
          ((float*)outv)[(size_t)r * 128 + col] = acc[reg] + badd;
      }
    }
  }
}

// ---- attention coefficients from bf16 xh ----
__global__ __launch_bounds__(256) void attn_coef_k(const uint* __restrict__ xbf,
                                                   const float* __restrict__ as_,
                                                   const float* __restrict__ ad_,
                                                   float* __restrict__ es,
                                                   float* __restrict__ ed) {
  const int idx = blockIdx.x * 256 + threadIdx.x;
  if (idx >= NH4) return;
  const int h = idx & 3;
  const int ab = h * 32;
  const uint* row = xbf + (size_t)(idx >> 2) * 64 + h * 16;
  float s = 0.f, d = 0.f;
#pragma unroll
  for (int i = 0; i < 16; i += 4) {
    const uint4 v = *(const uint4*)(row + i);
#define UNP(u, k)                                                        \
    {                                                                    \
      const float lo = __uint_as_float((u) << 16);                       \
      const float hi = __uint_as_float((u) & 0xffff0000u);               \
      s = fmaf(lo, as_[ab + (k)], fmaf(hi, as_[ab + (k) + 1], s));       \
      d = fmaf(lo, ad_[ab + (k)], fmaf(hi, ad_[ab + (k) + 1], d));       \
    }
    UNP(v.x, 2 * i) UNP(v.y, 2 * i + 2) UNP(v.z, 2 * i + 4) UNP(v.w, 2 * i + 6)
#undef UNP
  }
  es[idx] = s;
  ed[idx] = d;
}

// ---- CSR build: XCD-partitioned histogram ----
__global__ __launch_bounds__(256) void hist_k(const int* __restrict__ dst, int* __restrict__ counts) {
  const int g = blockIdx.x & 7;
  const int chunk = blockIdx.x >> 3;
  const int lo = g * (NN / 8);
  const int hi = lo + (NN / 8);
  const int e0 = chunk * SC_CHUNK;
  const int e1 = (e0 + SC_CHUNK < NE) ? e0 + SC_CHUNK : NE;
  for (int i = e0 + threadIdx.x; i < e1; i += 256) {
    const int d = dst[i];
    if (d >= lo && d < hi) atomicAdd(&counts[d], 1);
  }
}

// ---- two-level scan ----
__global__ __launch_bounds__(256) void scan_blk_k(const int* __restrict__ counts,
                                                  int* __restrict__ row_start,
                                                  int* __restrict__ blocksum) {
  __shared__ int sm[256];
  const int t = threadIdx.x;
  const int i = blockIdx.x * 256 + t;
  const int c = (i < NN) ? counts[i] : 0;
  sm[t] = c;
  __syncthreads();
#pragma unroll
  for (int off = 1; off < 256; off <<= 1) {
    const int v = (t >= off) ? sm[t - off] : 0;
    __syncthreads();
    sm[t] += v;
    __syncthreads();
  }
  if (i < NN) row_start[i] = sm[t] - c;
  if (t == 255) blocksum[blockIdx.x] = sm[255];
}

__global__ __launch_bounds__(512) void scan_top_k(const int* __restrict__ blocksum,
                                                  int* __restrict__ blockoff) {
  __shared__ int sm[512];
  const int t = threadIdx.x;
  const int c = (t < NBLK) ? blocksum[t] : 0;
  sm[t] = c;
  __syncthreads();
#pragma unroll
  for (int off = 1; off < 512; off <<= 1) {
    const int v = (t >= off) ? sm[t - off] : 0;
    __syncthreads();
    sm[t] += v;
    __syncthreads();
  }
  if (t < NBLK) blockoff[t] = sm[t] - c;
}

__global__ __launch_bounds__(256) void scan_fix_k(int* __restrict__ row_start,
                                                  const int* __restrict__ blockoff,
                                                  int* __restrict__ cursor) {
  const int i = blockIdx.x * 256 + threadIdx.x;
  if (i < NN) {
    const int v = row_start[i] + blockoff[blockIdx.x];
    row_start[i] = v;
    cursor[i] = v;
  }
  if (i == 0) row_start[NN] = NE;
}

// ---- XCD-partitioned scatter ----
__global__ __launch_bounds__(256) void scatter_k(const int* __restrict__ src,
                                                 const int* __restrict__ dst,
                                                 int* __restrict__ cursor,
                                                 int* __restrict__ csr_src) {
  const int g = blockIdx.x & 7;
  const int chunk = blockIdx.x >> 3;
  const int lo = g * (NN / 8);
  const int hi = lo + (NN / 8);
  const int e0 = chunk * SC_CHUNK;
  const int e1 = (e0 + SC_CHUNK < NE) ? e0 + SC_CHUNK : NE;
  for (int i = e0 + threadIdx.x; i < e1; i += 256) {
    const int d = dst[i];
    if (d >= lo && d < hi) {
      const int pos = atomicAdd(&cursor[d], 1);
      csr_src[pos] = src[i];
    }
  }
}

// ---- fused GAT aggregation: one wave per dst node, bf16 gathers, 8-way ILP ----
#define EDGE_BODY(sv)                                                      \
  {                                                                        \
    const int s_ = (sv);                                                   \
    float v_ = es[s_ * 4 + h] + edh;                                       \
    v_ = v_ > 0.f ? v_ : 0.2f * v_;                                        \
    const float w_ = __expf(v_);                                           \
    const uint m_ = xbf[(size_t)s_ * 64 + l];                              \
    const float mx = __uint_as_float(m_ << 16);                            \
    const float my = __uint_as_float(m_ & 0xffff0000u);                    \
    den += w_;                                                             \
    ax = fmaf(w_, mx, ax);                                                 \
    ay = fmaf(w_, my, ay);                                                 \
  }

__global__ __launch_bounds__(256) void gat_agg_k(const int* __restrict__ row_start,
                                                 const int* __restrict__ csr_src,
                                                 const float* __restrict__ es,
                                                 const float* __restrict__ ed,
                                                 const uint* __restrict__ xbf,
                                                 const float* __restrict__ base,
                                                 const float* __restrict__ bias,
                                                 float* __restrict__ out) {
  const int wid = (blockIdx.x * 256 + threadIdx.x) >> 6;  // node id
  if (wid >= NN) return;
  const int l = threadIdx.x & 63;   // lane: channels 2l (lo), 2l+1 (hi)
  const int h = l >> 4;             // head of both channels
  const float edh = ed[wid * 4 + h];
  const int beg = row_start[wid], end = row_start[wid + 1];
  float ax = 0.f, ay = 0.f, den = 0.f;
  int i = beg;
  for (; i + 8 <= end; i += 8) {
    const int s0 = csr_src[i],     s1 = csr_src[i + 1];
    const int s2 = csr_src[i + 2], s3 = csr_src[i + 3];
    const int s4 = csr_src[i + 4], s5 = csr_src[i + 5];
    const int s6 = csr_src[i + 6], s7 = csr_src[i + 7];
    EDGE_BODY(s0) EDGE_BODY(s1) EDGE_BODY(s2) EDGE_BODY(s3)
    EDGE_BODY(s4) EDGE_BODY(s5) EDGE_BODY(s6) EDGE_BODY(s7)
  }
  for (; i + 4 <= end; i += 4) {
    const int s0 = csr_src[i],     s1 = csr_src[i + 1];
    const int s2 = csr_src[i + 2], s3 = csr_src[i + 3];
    EDGE_BODY(s0) EDGE_BODY(s1) EDGE_BODY(s2) EDGE_BODY(s3)
  }
  for (; i < end; i++) EDGE_BODY(csr_src[i]);

  const float inv = den > 0.f ? 1.f / den : 0.f;
  float rx = ax * inv, ry = ay * inv;
  const int o = wid * 128 + l * 2;
  if (base) { rx += base[o]; ry += base[o + 1]; }
  if (bias) { rx += bias[l * 2]; ry += bias[l * 2 + 1]; }
  *(float2*)(out + o) = make_float2(rx, ry);
}

// ---- final projection: wave w -> channels 8w..8w+7; lane handles 2 nodes
// (halves scalar-pipe opW traffic per FLOP, doubles load ILP). ----
__global__ __launch_bounds__(256) void out_proj_k(const float* __restrict__ h0,
                                                  const float* __restrict__ h1,
                                                  const float* __restrict__ h2,
                                                  const float* __restrict__ opW,
                                                  const float* __restrict__ opb,
                                                  float* __restrict__ out) {
  const int cb = __builtin_amdgcn_readfirstlane((threadIdx.x >> 6) * 8);  // channel base
  const int l = threadIdx.x & 63;
  const int n0 = blockIdx.x * 128 + l;
  const int n1 = n0 + 64;
  const int m0 = n0 < NN ? n0 : NN - 1;
  const int m1 = n1 < NN ? n1 : NN - 1;

  float acc0[8], acc1[8];
#pragma unroll
  for (int j = 0; j < 8; j++) { acc0[j] = opb[cb + j]; acc1[j] = acc0[j]; }

  const float4* __restrict__ p0[3] = {(const float4*)(h0 + (size_t)m0 * 128),
                                      (const float4*)(h1 + (size_t)m0 * 128),
                                      (const float4*)(h2 + (size_t)m0 * 128)};
  const float4* __restrict__ p1[3] = {(const float4*)(h0 + (size_t)m1 * 128),
                                      (const float4*)(h1 + (size_t)m1 * 128),
                                      (const float4*)(h2 + (size_t)m1 * 128)};

#pragma unroll
  for (int seg = 0; seg < 3; seg++) {
    const float4* __restrict__ r0 = p0[seg];
    const float4* __restrict__ r1 = p1[seg];
    const int kofs = seg * 128;
    for (int k4 = 0; k4 < 32; k4++) {
      const float4 a0 = r0[k4];
      const float4 a1 = r1[k4];
      const float* __restrict__ wr = opW + (size_t)(kofs + k4 * 4) * 32 + cb;
#pragma unroll
      for (int j = 0; j < 8; j++) {
        acc0[j] = fmaf(a0.x, wr[j], acc0[j]);
        acc1[j] = fmaf(a1.x, wr[j], acc1[j]);
      }
#pragma unroll
      for (int j = 0; j < 8; j++) {
        acc0[j] = fmaf(a0.y, wr[32 + j], acc0[j]);
        acc1[j] = fmaf(a1.y, wr[32 + j], acc1[j]);
      }
#pragma unroll
      for (int j = 0; j < 8; j++) {
        acc0[j] = fmaf(a0.z, wr[64 + j], acc0[j]);
        acc1[j] = fmaf(a1.z, wr[64 + j], acc1[j]);
      }
#pragma unroll
      for (int j = 0; j < 8; j++) {
        acc0[j] = fmaf(a0.w, wr[96 + j], acc0[j]);
        acc1[j] = fmaf(a1.w, wr[96 + j], acc1[j]);
      }
    }
  }

  if (n0 < NN) {
    float* __restrict__ o = out + (size_t)n0 * 32 + cb;
    *(float4*)(o + 0) = make_float4(acc0[0], acc0[1], acc0[2], acc0[3]);
    *(float4*)(o + 4) = make_float4(acc0[4], acc0[5], acc0[6], acc0[7]);
  }
  if (n1 < NN) {
    float* __restrict__ o = out + (size_t)n1 * 32 + cb;
    *(float4*)(o + 0) = make_float4(acc1[0], acc1[1], acc1[2], acc1[3]);
    *(float4*)(o + 4) = make_float4(acc1[4], acc1[5], acc1[6], acc1[7]);
  }
}

extern "C" void kernel_launch(void* const* d_in, const int* in_sizes, int n_in,
                              void* d_out, int out_size, void* d_ws, size_t ws_size,
                              hipStream_t stream) {
  (void)in_sizes; (void)n_in; (void)out_size; (void)ws_size;
  const float* x  = (const float*)d_in[0];
  const int*   ei = (const int*)d_in[1];
  const int*  src = ei;
  const int*  dst = ei + NE;
  const float *W0 = (const float*)d_in[2],  *as0 = (const float*)d_in[3],
              *ad0 = (const float*)d_in[4], *b0 = (const float*)d_in[5];
  const float *W1 = (const float*)d_in[6],  *as1 = (const float*)d_in[7],
              *ad1 = (const float*)d_in[8], *b1 = (const float*)d_in[9];
  const float *W2 = (const float*)d_in[10], *as2 = (const float*)d_in[11],
              *ad2 = (const float*)d_in[12], *b2 = (const float*)d_in[13];
  const float *llW = (const float*)d_in[14], *llb = (const float*)d_in[15];
  const float *opW = (const float*)d_in[16], *opb = (const float*)d_in[17];

  float* ws    = (float*)d_ws;
  float* h0f   = ws;             // NHC
  float* h1f   = h0f + NHC;      // NHC
  float* h2f   = h1f + NHC;      // NHC
  uint*  xbf   = (uint*)(h2f + NHC);      // NHC/2 uints (bf16 xh)
  float* es    = (float*)(xbf + NHC / 2); // NH4
  float* ed    = es + NH4;       // NH4
  int* row_start = (int*)(ed + NH4);      // NN+1
  int* cursor    = row_start + NN + 1;    // NN
  int* counts    = cursor + NN;           // NN
  int* csr_src   = counts + NN;           // NE
  int* blocksum  = csr_src + NE;          // NBLK
  int* blockoff  = blocksum + NBLK;       // NBLK

  const dim3 blk(256);
  // ---------- CSR build (edges shared by all 3 layers) ----------
  hipMemsetAsync(counts, 0, (size_t)NN * 4, stream);
  hist_k<<<SC_NCHUNK * 8, blk, 0, stream>>>(dst, counts);
  scan_blk_k<<<NBLK, blk, 0, stream>>>(counts, row_start, blocksum);
  scan_top_k<<<1, 512, 0, stream>>>(blocksum, blockoff);
  scan_fix_k<<<NBLK, blk, 0, stream>>>(row_start, blockoff, cursor);
  scatter_k<<<SC_NCHUNK * 8, blk, 0, stream>>>(src, dst, cursor, csr_src);
  // ---------- layer 0 ----------
  gemm128_k<true><<<1563, blk, 0, stream>>>(x, W0, xbf, nullptr, nullptr);
  attn_coef_k<<<1563, blk, 0, stream>>>(xbf, as0, ad0, es, ed);
  gat_agg_k<<<25000, blk, 0, stream>>>(row_start, csr_src, es, ed, xbf, nullptr, b0, h0f);
  // ---------- layer 1 ----------
  gemm128_k<true><<<1563, blk, 0, stream>>>(h0f, W1, xbf, nullptr, nullptr);
  attn_coef_k<<<1563, blk, 0, stream>>>(xbf, as1, ad1, es, ed);
  gat_agg_k<<<25000, blk, 0, stream>>>(row_start, csr_src, es, ed, xbf, h0f, b1, h1f);
  // ---------- layer 2 ----------
  gemm128_k<false><<<1563, blk, 0, stream>>>(h1f, llW, h2f, llb, b2);  // h2 base = h1@llW + llb + b2
  gemm128_k<true><<<1563, blk, 0, stream>>>(h1f, W2, xbf, nullptr, nullptr);
  attn_coef_k<<<1563, blk, 0, stream>>>(xbf, as2, ad2, es, ed);
  gat_agg_k<<<25000, blk, 0, stream>>>(row_start, csr_src, es, ed, xbf, h2f, nullptr, h2f);
  // ---------- output head ----------
  out_proj_k<<<782, blk, 0, stream>>>(h0f, h1f, h2f, opW, opb, (float*)d_out);
}

// Round 10
// 582.316 us; speedup vs baseline: 1.3401x; 1.1363x over previous
//
#include <hip/hip_runtime.h>
#include <hip/hip_bf16.h>

#define NN  100000
#define NE  1600000
#define NH4 400000      // N*H
#define NHC 12800000    // N*HC
#define NBLK 391        // ceil(NN/256)
#define SC_CHUNK 2048
#define SC_NCHUNK ((NE + SC_CHUNK - 1) / SC_CHUNK)  // 782

typedef __attribute__((ext_vector_type(8))) short bf16x8;
typedef __attribute__((ext_vector_type(4))) float f32x4;

__device__ __forceinline__ ushort f2bf(float f) {  // RNE f32 -> bf16 bits
  uint u = __float_as_uint(f);
  u += 0x7fff + ((u >> 16) & 1);
  return (ushort)(u >> 16);
}
__device__ __forceinline__ uint pack2(float a, float b) {
  return (uint)f2bf(a) | ((uint)f2bf(b) << 16);
}
__device__ __forceinline__ float blo(uint u) { return __uint_as_float(u << 16); }
__device__ __forceinline__ float bhi(uint u) { return __uint_as_float(u & 0xffff0000u); }

// ---- MFMA GEMM: out[N,128](bf16) = A[N,128] @ W[128,128] (+ bias1 + bias2) ----
// A input f32 (layer 0) or bf16 (h buffers). A,W staged bf16 in LDS, XOR
// swizzle (uint_idx ^= (row&7)<<2 on both write & read).
template <bool ABF16>
__global__ __launch_bounds__(256) void gemm128_k(const void* __restrict__ Av,
                                                 const float* __restrict__ W,
                                                 ushort* __restrict__ out,
                                                 const float* __restrict__ bias1,
                                                 const float* __restrict__ bias2) {
  __shared__ uint As[64 * 64];    // 16 KB  (row r: 64 uints = 128 bf16)
  __shared__ uint Wt[128 * 64];   // 32 KB  (row n: 64 uints = 128 bf16, k-major)
  const int tid = threadIdx.x;
  const int row0 = blockIdx.x * 64;

  // ---- stage A ----
  if constexpr (ABF16) {
    const uint4* __restrict__ Ag = (const uint4*)((const uint*)Av + (size_t)row0 * 64);
#pragma unroll
    for (int i = 0; i < 4; i++) {
      const int idx = tid + 256 * i;        // uint4 idx over 64x16
      const int r = idx >> 4, c4 = idx & 15;
      uint4 v = make_uint4(0u, 0u, 0u, 0u);
      if (row0 + r < NN) v = Ag[idx];
      const uint off = (uint)(r * 64 + c4 * 4) ^ (uint)((r & 7) << 2);
      *(uint4*)&As[off] = v;
    }
  } else {
    const float4* __restrict__ Ag = (const float4*)((const float*)Av + (size_t)row0 * 128);
#pragma unroll
    for (int i = 0; i < 8; i++) {
      const int idx = tid + 256 * i;        // float4 idx over 64x32
      const int r = idx >> 5, k4 = idx & 31;
      float4 a = make_float4(0.f, 0.f, 0.f, 0.f);
      if (row0 + r < NN) a = Ag[idx];
      uint2 p;
      p.x = pack2(a.x, a.y);
      p.y = pack2(a.z, a.w);
      const uint off = (uint)(r * 64 + k4 * 2) ^ (uint)((r & 7) << 2);
      *(uint2*)&As[off] = p;
    }
  }
  // ---- stage W transposed: Wt[n][k] bf16, swizzled ----
  {
#pragma unroll
    for (int i = 0; i < 8; i++) {
      const int cid = tid + 256 * i;        // (n, k8) chunk
      const int n = cid & 127;
      const int k8 = cid >> 7;              // 0..15
      float v[8];
#pragma unroll
      for (int j = 0; j < 8; j++) v[j] = W[(size_t)(k8 * 8 + j) * 128 + n];
      uint4 p;
      p.x = pack2(v[0], v[1]);
      p.y = pack2(v[2], v[3]);
      p.z = pack2(v[4], v[5]);
      p.w = pack2(v[6], v[7]);
      const uint off = (uint)(n * 64 + k8 * 4) ^ (uint)((n & 7) << 2);
      *(uint4*)&Wt[off] = p;
    }
  }
  __syncthreads();

  const int w = tid >> 6, l = tid & 63;
  const int lrow = l & 15;
  const int lku = (l >> 4) * 4;   // uint offset of lane's k-base (8 bf16 = 4 uints)

  bf16x8 afrag[4];
#pragma unroll
  for (int kc = 0; kc < 4; kc++) {
    const int r = w * 16 + lrow;
    const uint off = (uint)(r * 64 + lku + kc * 16) ^ (uint)((r & 7) << 2);
    afrag[kc] = *(const bf16x8*)&As[off];
  }

#pragma unroll
  for (int nt = 0; nt < 8; nt++) {
    const int n = nt * 16 + lrow;
    f32x4 acc = {0.f, 0.f, 0.f, 0.f};
#pragma unroll
    for (int kc = 0; kc < 4; kc++) {
      const uint off = (uint)(n * 64 + lku + kc * 16) ^ (uint)((n & 7) << 2);
      const bf16x8 bfrag = *(const bf16x8*)&Wt[off];
      acc = __builtin_amdgcn_mfma_f32_16x16x32_bf16(afrag[kc], bfrag, acc, 0, 0, 0);
    }
    const int col = n;  // D col = l&15 within tile
    float badd = 0.f;
    if (bias1) badd += bias1[col];
    if (bias2) badd += bias2[col];
#pragma unroll
    for (int reg = 0; reg < 4; reg++) {
      const int r = row0 + w * 16 + (l >> 4) * 4 + reg;
      if (r < NN) out[(size_t)r * 128 + col] = f2bf(acc[reg] + badd);
    }
  }
}

// ---- attention coefficients from bf16 xh ----
__global__ __launch_bounds__(256) void attn_coef_k(const uint* __restrict__ xbf,
                                                   const float* __restrict__ as_,
                                                   const float* __restrict__ ad_,
                                                   float* __restrict__ es,
                                                   float* __restrict__ ed) {
  const int idx = blockIdx.x * 256 + threadIdx.x;
  if (idx >= NH4) return;
  const int h = idx & 3;
  const int ab = h * 32;
  const uint* row = xbf + (size_t)(idx >> 2) * 64 + h * 16;
  float s = 0.f, d = 0.f;
#pragma unroll
  for (int i = 0; i < 16; i += 4) {
    const uint4 v = *(const uint4*)(row + i);
#define UNP(u, k)                                                        \
    {                                                                    \
      const float lo = blo(u), hi = bhi(u);                              \
      s = fmaf(lo, as_[ab + (k)], fmaf(hi, as_[ab + (k) + 1], s));       \
      d = fmaf(lo, ad_[ab + (k)], fmaf(hi, ad_[ab + (k) + 1], d));       \
    }
    UNP(v.x, 2 * i) UNP(v.y, 2 * i + 2) UNP(v.z, 2 * i + 4) UNP(v.w, 2 * i + 6)
#undef UNP
  }
  es[idx] = s;
  ed[idx] = d;
}

// ---- CSR build: XCD-partitioned histogram ----
__global__ __launch_bounds__(256) void hist_k(const int* __restrict__ dst, int* __restrict__ counts) {
  const int g = blockIdx.x & 7;
  const int chunk = blockIdx.x >> 3;
  const int lo = g * (NN / 8);
  const int hi = lo + (NN / 8);
  const int e0 = chunk * SC_CHUNK;
  const int e1 = (e0 + SC_CHUNK < NE) ? e0 + SC_CHUNK : NE;
  for (int i = e0 + threadIdx.x; i < e1; i += 256) {
    const int d = dst[i];
    if (d >= lo && d < hi) atomicAdd(&counts[d], 1);
  }
}

// ---- two-level scan ----
__global__ __launch_bounds__(256) void scan_blk_k(const int* __restrict__ counts,
                                                  int* __restrict__ row_start,
                                                  int* __restrict__ blocksum) {
  __shared__ int sm[256];
  const int t = threadIdx.x;
  const int i = blockIdx.x * 256 + t;
  const int c = (i < NN) ? counts[i] : 0;
  sm[t] = c;
  __syncthreads();
#pragma unroll
  for (int off = 1; off < 256; off <<= 1) {
    const int v = (t >= off) ? sm[t - off] : 0;
    __syncthreads();
    sm[t] += v;
    __syncthreads();
  }
  if (i < NN) row_start[i] = sm[t] - c;
  if (t == 255) blocksum[blockIdx.x] = sm[255];
}

__global__ __launch_bounds__(512) void scan_top_k(const int* __restrict__ blocksum,
                                                  int* __restrict__ blockoff) {
  __shared__ int sm[512];
  const int t = threadIdx.x;
  const int c = (t < NBLK) ? blocksum[t] : 0;
  sm[t] = c;
  __syncthreads();
#pragma unroll
  for (int off = 1; off < 512; off <<= 1) {
    const int v = (t >= off) ? sm[t - off] : 0;
    __syncthreads();
    sm[t] += v;
    __syncthreads();
  }
  if (t < NBLK) blockoff[t] = sm[t] - c;
}

__global__ __launch_bounds__(256) void scan_fix_k(int* __restrict__ row_start,
                                                  const int* __restrict__ blockoff,
                                                  int* __restrict__ cursor) {
  const int i = blockIdx.x * 256 + threadIdx.x;
  if (i < NN) {
    const int v = row_start[i] + blockoff[blockIdx.x];
    row_start[i] = v;
    cursor[i] = v;
  }
  if (i == 0) row_start[NN] = NE;
}

// ---- XCD-partitioned scatter ----
__global__ __launch_bounds__(256) void scatter_k(const int* __restrict__ src,
                                                 const int* __restrict__ dst,
                                                 int* __restrict__ cursor,
                                                 int* __restrict__ csr_src) {
  const int g = blockIdx.x & 7;
  const int chunk = blockIdx.x >> 3;
  const int lo = g * (NN / 8);
  const int hi = lo + (NN / 8);
  const int e0 = chunk * SC_CHUNK;
  const int e1 = (e0 + SC_CHUNK < NE) ? e0 + SC_CHUNK : NE;
  for (int i = e0 + threadIdx.x; i < e1; i += 256) {
    const int d = dst[i];
    if (d >= lo && d < hi) {
      const int pos = atomicAdd(&cursor[d], 1);
      csr_src[pos] = src[i];
    }
  }
}

// ---- fused GAT aggregation: one wave per dst node, bf16 gathers + bf16 h ----
#define EDGE_BODY(sv)                                                      \
  {                                                                        \
    const int s_ = (sv);                                                   \
    float v_ = es[s_ * 4 + h] + edh;                                       \
    v_ = v_ > 0.f ? v_ : 0.2f * v_;                                        \
    const float w_ = __expf(v_);                                           \
    const uint m_ = xbf[(size_t)s_ * 64 + l];                              \
    den += w_;                                                             \
    ax = fmaf(w_, blo(m_), ax);                                            \
    ay = fmaf(w_, bhi(m_), ay);                                            \
  }

__global__ __launch_bounds__(256) void gat_agg_k(const int* __restrict__ row_start,
                                                 const int* __restrict__ csr_src,
                                                 const float* __restrict__ es,
                                                 const float* __restrict__ ed,
                                                 const uint* __restrict__ xbf,
                                                 const ushort* __restrict__ base,
                                                 const float* __restrict__ bias,
                                                 ushort* __restrict__ out) {
  const int wid = (blockIdx.x * 256 + threadIdx.x) >> 6;  // node id
  if (wid >= NN) return;
  const int l = threadIdx.x & 63;   // lane: channels 2l (lo), 2l+1 (hi)
  const int h = l >> 4;             // head of both channels
  const float edh = ed[wid * 4 + h];
  const int beg = row_start[wid], end = row_start[wid + 1];
  float ax = 0.f, ay = 0.f, den = 0.f;
  int i = beg;
  for (; i + 8 <= end; i += 8) {
    const int s0 = csr_src[i],     s1 = csr_src[i + 1];
    const int s2 = csr_src[i + 2], s3 = csr_src[i + 3];
    const int s4 = csr_src[i + 4], s5 = csr_src[i + 5];
    const int s6 = csr_src[i + 6], s7 = csr_src[i + 7];
    EDGE_BODY(s0) EDGE_BODY(s1) EDGE_BODY(s2) EDGE_BODY(s3)
    EDGE_BODY(s4) EDGE_BODY(s5) EDGE_BODY(s6) EDGE_BODY(s7)
  }
  for (; i + 4 <= end; i += 4) {
    const int s0 = csr_src[i],     s1 = csr_src[i + 1];
    const int s2 = csr_src[i + 2], s3 = csr_src[i + 3];
    EDGE_BODY(s0) EDGE_BODY(s1) EDGE_BODY(s2) EDGE_BODY(s3)
  }
  for (; i < end; i++) EDGE_BODY(csr_src[i]);

  const float inv = den > 0.f ? 1.f / den : 0.f;
  float rx = ax * inv, ry = ay * inv;
  const size_t o = (size_t)wid * 64 + l;   // uint index into bf16 row
  if (base) {
    const uint b = ((const uint*)base)[o];
    rx += blo(b); ry += bhi(b);
  }
  if (bias) { rx += bias[l * 2]; ry += bias[l * 2 + 1]; }
  ((uint*)out)[o] = pack2(rx, ry);
}

// ---- final projection: wave w -> channels 8w..8w+7; lane = node (bf16 h) ----
__global__ __launch_bounds__(256) void out_proj_k(const ushort* __restrict__ h0,
                                                  const ushort* __restrict__ h1,
                                                  const ushort* __restrict__ h2,
                                                  const float* __restrict__ opW,
                                                  const float* __restrict__ opb,
                                                  float* __restrict__ out) {
  const int cb = __builtin_amdgcn_readfirstlane((threadIdx.x >> 6) * 8);  // channel base
  const int l = threadIdx.x & 63;
  const int n = blockIdx.x * 64 + l;
  if (n >= NN) return;

  float acc[8];
#pragma unroll
  for (int j = 0; j < 8; j++) acc[j] = opb[cb + j];

  const uint4* __restrict__ rp[3] = {
      (const uint4*)((const uint*)h0 + (size_t)n * 64),
      (const uint4*)((const uint*)h1 + (size_t)n * 64),
      (const uint4*)((const uint*)h2 + (size_t)n * 64)};

#pragma unroll
  for (int seg = 0; seg < 3; seg++) {
    const uint4* __restrict__ r = rp[seg];
    for (int k8 = 0; k8 < 16; k8++) {        // 8 bf16 per iter
      const uint4 v = r[k8];
      float av[8];
      av[0] = blo(v.x); av[1] = bhi(v.x);
      av[2] = blo(v.y); av[3] = bhi(v.y);
      av[4] = blo(v.z); av[5] = bhi(v.z);
      av[6] = blo(v.w); av[7] = bhi(v.w);
      const float* __restrict__ wr = opW + (size_t)(seg * 128 + k8 * 8) * 32 + cb;
#pragma unroll
      for (int q = 0; q < 8; q++)
#pragma unroll
        for (int j = 0; j < 8; j++)
          acc[j] = fmaf(av[q], wr[q * 32 + j], acc[j]);
    }
  }

  float* __restrict__ o = out + (size_t)n * 32 + cb;
  *(float4*)(o + 0) = make_float4(acc[0], acc[1], acc[2], acc[3]);
  *(float4*)(o + 4) = make_float4(acc[4], acc[5], acc[6], acc[7]);
}

extern "C" void kernel_launch(void* const* d_in, const int* in_sizes, int n_in,
                              void* d_out, int out_size, void* d_ws, size_t ws_size,
                              hipStream_t stream) {
  (void)in_sizes; (void)n_in; (void)out_size; (void)ws_size;
  const float* x  = (const float*)d_in[0];
  const int*   ei = (const int*)d_in[1];
  const int*  src = ei;
  const int*  dst = ei + NE;
  const float *W0 = (const float*)d_in[2],  *as0 = (const float*)d_in[3],
              *ad0 = (const float*)d_in[4], *b0 = (const float*)d_in[5];
  const float *W1 = (const float*)d_in[6],  *as1 = (const float*)d_in[7],
              *ad1 = (const float*)d_in[8], *b1 = (const float*)d_in[9];
  const float *W2 = (const float*)d_in[10], *as2 = (const float*)d_in[11],
              *ad2 = (const float*)d_in[12], *b2 = (const float*)d_in[13];
  const float *llW = (const float*)d_in[14], *llb = (const float*)d_in[15];
  const float *opW = (const float*)d_in[16], *opb = (const float*)d_in[17];

  char* w = (char*)d_ws;
  ushort* h0b = (ushort*)w; w += (size_t)NHC * 2;
  ushort* h1b = (ushort*)w; w += (size_t)NHC * 2;
  ushort* h2b = (ushort*)w; w += (size_t)NHC * 2;
  uint*   xbf = (uint*)w;   w += (size_t)NHC * 2;   // NHC/2 uints
  float*  es  = (float*)w;  w += (size_t)NH4 * 4;
  float*  ed  = (float*)w;  w += (size_t)NH4 * 4;
  int* row_start = (int*)w; w += (size_t)(NN + 1) * 4;
  int* cursor    = (int*)w; w += (size_t)NN * 4;
  int* counts    = (int*)w; w += (size_t)NN * 4;
  int* csr_src   = (int*)w; w += (size_t)NE * 4;
  int* blocksum  = (int*)w; w += (size_t)NBLK * 4;
  int* blockoff  = (int*)w;

  const dim3 blk(256);
  // ---------- CSR build (edges shared by all 3 layers) ----------
  hipMemsetAsync(counts, 0, (size_t)NN * 4, stream);
  hist_k<<<SC_NCHUNK * 8, blk, 0, stream>>>(dst, counts);
  scan_blk_k<<<NBLK, blk, 0, stream>>>(counts, row_start, blocksum);
  scan_top_k<<<1, 512, 0, stream>>>(blocksum, blockoff);
  scan_fix_k<<<NBLK, blk, 0, stream>>>(row_start, blockoff, cursor);
  scatter_k<<<SC_NCHUNK * 8, blk, 0, stream>>>(src, dst, cursor, csr_src);
  // ---------- layer 0 ----------
  gemm128_k<false><<<1563, blk, 0, stream>>>(x, W0, (ushort*)xbf, nullptr, nullptr);
  attn_coef_k<<<1563, blk, 0, stream>>>(xbf, as0, ad0, es, ed);
  gat_agg_k<<<25000, blk, 0, stream>>>(row_start, csr_src, es, ed, xbf, nullptr, b0, h0b);
  // ---------- layer 1 ----------
  gemm128_k<true><<<1563, blk, 0, stream>>>(h0b, W1, (ushort*)xbf, nullptr, nullptr);
  attn_coef_k<<<1563, blk, 0, stream>>>(xbf, as1, ad1, es, ed);
  gat_agg_k<<<25000, blk, 0, stream>>>(row_start, csr_src, es, ed, xbf, h0b, b1, h1b);
  // ---------- layer 2 ----------
  gemm128_k<true><<<1563, blk, 0, stream>>>(h1b, llW, h2b, llb, b2);  // h2 base = h1@llW + llb + b2
  gemm128_k<true><<<1563, blk, 0, stream>>>(h1b, W2, (ushort*)xbf, nullptr, nullptr);
  attn_coef_k<<<1563, blk, 0, stream>>>(xbf, as2, ad2, es, ed);
  gat_agg_k<<<25000, blk, 0, stream>>>(row_start, csr_src, es, ed, xbf, h2b, nullptr, h2b);
  // ---------- output head ----------
  out_proj_k<<<1563, blk, 0, stream>>>(h0b, h1b, h2b, opW, opb, (float*)d_out);
}